// Round 3
// baseline (556.641 us; speedup 1.0000x reference)
//
#include <hip/hip_runtime.h>

// Fused spatio-temporal GCN, MI355X (gfx950), fp32 (no fp32 MFMA -> vector ALU).
// T=128, N=256, H=4, EMB=16, IN_DIMS=5, HID=64.
//
// R3: latency fix. Whole working set is LLC-resident (R2: FETCH 78MB < adj_s),
// so the limiter is per-wave stall, not HBM BW. Changes vs R2:
//  - 1-wave (64-thread) blocks, NO __syncthreads anywhere.
//  - Software-pipelined staging with RAW COUNTED vmcnt (T4): prologue stages
//    two 16KB chunks; steady state waits vmcnt(16) (= oldest chunk retired,
//    newest still in flight), consumes, re-stages. Pipe never drains to 0.
//  - lgkmcnt(0) guard before overwriting a just-consumed buffer.
//  - aux=0 everywhere (NT experiment removed; it only traded HBM for latency).
// LDS layout unchanged from R2 (256B rows, 4-bit XOR swizzle, measured 0 bank
// conflicts): stage pre-swizzles the GLOBAL source so linear global_load_lds
// dest lands swizzled; tile_read applies the same involution.

#define T_DIM 128
#define N_DIM 256
#define H_DIM 4

typedef const __attribute__((address_space(1))) void* gas_ptr;
typedef __attribute__((address_space(3))) void* las_ptr;

#define WAITV16() asm volatile("s_waitcnt vmcnt(16)" ::: "memory")
#define WAITV0()  asm volatile("s_waitcnt vmcnt(0)"  ::: "memory")
#define LGKM0()   asm volatile("s_waitcnt lgkmcnt(0)" ::: "memory")

// Stage a [64 rows][64 floats] (16KB) chunk from global (row stride rs bytes,
// byte-column offset koff) into LDS tile. 16 x 1KB-contiguous global_load_lds.
__device__ __forceinline__ void stage_chunk(const char* __restrict__ gslice, int rs, int koff,
                                            float* tile, int lane) {
#pragma unroll
  for (int i = 0; i < 16; ++i) {
    int p = (i << 10) + (lane << 4);
    int ps = p ^ (((p >> 8) & 15) << 4);
    const char* src = gslice + (ps >> 8) * rs + koff + (ps & 255);
    __builtin_amdgcn_global_load_lds((gas_ptr)src, (las_ptr)((char*)tile + p), 16, 0, 0);
  }
}

// Read 4 consecutive floats of row `row` at float-index kk (multiple of 4).
__device__ __forceinline__ float4 tile_read(const float* tile, int row, int kk) {
  int byt = (row << 8) + (kk << 2);
  byt ^= (row & 15) << 4;
  return *(const float4*)((const char*)tile + byt);
}

// ---------------- K1: l1t -> B_pack[t][h][n][8..23]; h==0 also fills spa cols 0..4 ----
__global__ __launch_bounds__(64) void k1_l1t(
    const float* __restrict__ graph, const float* __restrict__ adj_t,
    const float* __restrict__ W_t1, const float* __restrict__ a_t1,
    float* __restrict__ B_pack)
{
    __shared__ __align__(16) float tile[2][4096];
    const int n = blockIdx.x, h = blockIdx.y, rb = blockIdx.z;
    const int lane = threadIdx.x;
    const int t = rb * 64 + lane;

    const char* aslice = (const char*)(adj_t + ((size_t)(n * H_DIM + h) * T_DIM + rb * 64) * T_DIM);

    stage_chunk(aslice, T_DIM * 4, 0,   tile[0], lane);
    stage_chunk(aslice, T_DIM * 4, 256, tile[1], lane);

    float acc[5] = {0.f, 0.f, 0.f, 0.f, 0.f};
#pragma unroll
    for (int kc = 0; kc < 2; ++kc) {
        if (kc == 0) { WAITV16(); } else { WAITV0(); }
        const float* tl = tile[kc];
        for (int kk = 0; kk < 64; kk += 4) {
            const float4 a4 = tile_read(tl, lane, kk);
            const float av[4] = {a4.x, a4.y, a4.z, a4.w};
#pragma unroll
            for (int j = 0; j < 4; ++j) {
                const int k = kc * 64 + kk + j;
                const float* b = graph + (k * N_DIM + n) * 6 + 1;  // uniform -> s_load
                const float a = av[j];
#pragma unroll
                for (int d = 0; d < 5; ++d) acc[d] = fmaf(a, b[d], acc[d]);
            }
        }
    }

    const float alpha = a_t1[0];
    float v[16];
#pragma unroll
    for (int e = 0; e < 16; ++e) {
        float s = 0.f;
#pragma unroll
        for (int d = 0; d < 5; ++d) s = fmaf(acc[d], W_t1[e * 5 + d], s);
        v[e] = (s >= 0.f) ? s : alpha * s;
    }
    float* dst = B_pack + ((size_t)(t * H_DIM + h) * N_DIM + n) * 24 + 8;
#pragma unroll
    for (int q = 0; q < 4; ++q)
        *(float4*)(dst + 4 * q) = make_float4(v[4*q], v[4*q+1], v[4*q+2], v[4*q+3]);

    if (h == 0) {
        const float* g = graph + (t * N_DIM + n) * 6 + 1;
        float s0 = g[0], s1 = g[1], s2 = g[2], s3 = g[3], s4 = g[4];
#pragma unroll
        for (int hh = 0; hh < H_DIM; ++hh) {
            float* sd = B_pack + ((size_t)(t * H_DIM + hh) * N_DIM + n) * 24;
            sd[0] = s0; sd[1] = s1; sd[2] = s2; sd[3] = s3; sd[4] = s4;
        }
    }
}

// ---------------- K2: C = adj_s[t,h] @ B_pack -> l1s (B_pack2) + Ht (Ht_f) ----------
__global__ __launch_bounds__(64) void k2_l1s_ht(
    const float* __restrict__ adj_s, const float* __restrict__ B_pack,
    const float* __restrict__ W_s1, const float* __restrict__ a_s1,
    const float* __restrict__ W_t2, const float* __restrict__ a_t2,
    float* __restrict__ B_pack2, float* __restrict__ Ht_f)
{
    __shared__ __align__(16) float tile[2][4096];
    const int t = blockIdx.x, h = blockIdx.y, q = blockIdx.z;
    const int lane = threadIdx.x;
    const int n = q * 64 + lane;

    const char* aslice = (const char*)(adj_s + ((size_t)(t * H_DIM + h) * N_DIM + q * 64) * N_DIM);
    const float* bp = B_pack + (size_t)(t * H_DIM + h) * (N_DIM * 24);

    float acc[21];
#pragma unroll
    for (int i = 0; i < 21; ++i) acc[i] = 0.f;

    stage_chunk(aslice, N_DIM * 4, 0,   tile[0], lane);
    stage_chunk(aslice, N_DIM * 4, 256, tile[1], lane);

#pragma unroll
    for (int kc = 0; kc < 4; ++kc) {
        if (kc < 3) { WAITV16(); } else { WAITV0(); }
        const float* tl = tile[kc & 1];
        for (int kk = 0; kk < 64; kk += 4) {
            const float4 a4 = tile_read(tl, lane, kk);
            const float av[4] = {a4.x, a4.y, a4.z, a4.w};
#pragma unroll
            for (int j = 0; j < 4; ++j) {
                const float* b = bp + (kc * 64 + kk + j) * 24;  // uniform -> s_load
                const float a = av[j];
                const float4 b0 = *(const float4*)(b);
                const float  b4 = b[4];
                const float4 c0 = *(const float4*)(b + 8);
                const float4 c1 = *(const float4*)(b + 12);
                const float4 c2 = *(const float4*)(b + 16);
                const float4 c3 = *(const float4*)(b + 20);
                acc[0] = fmaf(a, b0.x, acc[0]);  acc[1] = fmaf(a, b0.y, acc[1]);
                acc[2] = fmaf(a, b0.z, acc[2]);  acc[3] = fmaf(a, b0.w, acc[3]);
                acc[4] = fmaf(a, b4,   acc[4]);
                acc[5]  = fmaf(a, c0.x, acc[5]);  acc[6]  = fmaf(a, c0.y, acc[6]);
                acc[7]  = fmaf(a, c0.z, acc[7]);  acc[8]  = fmaf(a, c0.w, acc[8]);
                acc[9]  = fmaf(a, c1.x, acc[9]);  acc[10] = fmaf(a, c1.y, acc[10]);
                acc[11] = fmaf(a, c1.z, acc[11]); acc[12] = fmaf(a, c1.w, acc[12]);
                acc[13] = fmaf(a, c2.x, acc[13]); acc[14] = fmaf(a, c2.y, acc[14]);
                acc[15] = fmaf(a, c2.z, acc[15]); acc[16] = fmaf(a, c2.w, acc[16]);
                acc[17] = fmaf(a, c3.x, acc[17]); acc[18] = fmaf(a, c3.y, acc[18]);
                acc[19] = fmaf(a, c3.z, acc[19]); acc[20] = fmaf(a, c3.w, acc[20]);
            }
        }
        if (kc < 2) {  // re-stage just-consumed buffer with chunk kc+2
            LGKM0();   // ds_reads of this buffer must complete before DMA overwrite
            stage_chunk(aslice, N_DIM * 4, (kc + 2) * 256, tile[kc & 1], lane);
        }
    }

    // l1s = prelu(C_spa @ W_s1^T) -> B_pack2[n][h][t][e]
    {
        const float alpha = a_s1[0];
        float v[16];
#pragma unroll
        for (int e = 0; e < 16; ++e) {
            float s = 0.f;
#pragma unroll
            for (int d = 0; d < 5; ++d) s = fmaf(acc[d], W_s1[e * 5 + d], s);
            v[e] = (s >= 0.f) ? s : alpha * s;
        }
        float* dst = B_pack2 + ((size_t)(n * H_DIM + h) * T_DIM + t) * 16;
#pragma unroll
        for (int qq = 0; qq < 4; ++qq)
            *(float4*)(dst + 4 * qq) = make_float4(v[4*qq], v[4*qq+1], v[4*qq+2], v[4*qq+3]);
    }
    // Ht = prelu(C_l1t @ W_t2^T) -> Ht_f[n][t][h][e]
    {
        const float alpha = a_t2[0];
        float v[16];
#pragma unroll
        for (int e = 0; e < 16; ++e) {
            float s = 0.f;
#pragma unroll
            for (int e2 = 0; e2 < 16; ++e2) s = fmaf(acc[5 + e2], W_t2[e * 16 + e2], s);
            v[e] = (s >= 0.f) ? s : alpha * s;
        }
        float* dst = Ht_f + ((size_t)(n * T_DIM + t) * H_DIM + h) * 16;
#pragma unroll
        for (int qq = 0; qq < 4; ++qq)
            *(float4*)(dst + 4 * qq) = make_float4(v[4*qq], v[4*qq+1], v[4*qq+2], v[4*qq+3]);
    }
}

// ---------------- K3: Hs + fused MLP/softmax/blend -> out[n][t][h][:] ----------------
__global__ __launch_bounds__(64) void k3_hs_mlp(
    const float* __restrict__ adj_t, const float* __restrict__ B_pack2,
    const float* __restrict__ W_s2, const float* __restrict__ a_s2,
    const float* __restrict__ Ht_f,
    const float* __restrict__ Wm1, const float* __restrict__ bm1,
    const float* __restrict__ Wm2, const float* __restrict__ bm2,
    float* __restrict__ out)
{
    __shared__ __align__(16) float tile[2][4096];
    const int n = blockIdx.x, h = blockIdx.y, rb = blockIdx.z;
    const int lane = threadIdx.x;
    const int t = rb * 64 + lane;

    const char* aslice = (const char*)(adj_t + ((size_t)(n * H_DIM + h) * T_DIM + rb * 64) * T_DIM);
    const float* bp = B_pack2 + (size_t)(n * H_DIM + h) * (T_DIM * 16);

    stage_chunk(aslice, T_DIM * 4, 0,   tile[0], lane);
    stage_chunk(aslice, T_DIM * 4, 256, tile[1], lane);

    float acc[16];
#pragma unroll
    for (int i = 0; i < 16; ++i) acc[i] = 0.f;

#pragma unroll
    for (int kc = 0; kc < 2; ++kc) {
        if (kc == 0) { WAITV16(); } else { WAITV0(); }
        const float* tl = tile[kc];
        for (int kk = 0; kk < 64; kk += 4) {
            const float4 a4 = tile_read(tl, lane, kk);
            const float av[4] = {a4.x, a4.y, a4.z, a4.w};
#pragma unroll
            for (int j = 0; j < 4; ++j) {
                const float* b = bp + (kc * 64 + kk + j) * 16;  // uniform -> s_load
                const float a = av[j];
                const float4 c0 = *(const float4*)(b);
                const float4 c1 = *(const float4*)(b + 4);
                const float4 c2 = *(const float4*)(b + 8);
                const float4 c3 = *(const float4*)(b + 12);
                acc[0]  = fmaf(a, c0.x, acc[0]);  acc[1]  = fmaf(a, c0.y, acc[1]);
                acc[2]  = fmaf(a, c0.z, acc[2]);  acc[3]  = fmaf(a, c0.w, acc[3]);
                acc[4]  = fmaf(a, c1.x, acc[4]);  acc[5]  = fmaf(a, c1.y, acc[5]);
                acc[6]  = fmaf(a, c1.z, acc[6]);  acc[7]  = fmaf(a, c1.w, acc[7]);
                acc[8]  = fmaf(a, c2.x, acc[8]);  acc[9]  = fmaf(a, c2.y, acc[9]);
                acc[10] = fmaf(a, c2.z, acc[10]); acc[11] = fmaf(a, c2.w, acc[11]);
                acc[12] = fmaf(a, c3.x, acc[12]); acc[13] = fmaf(a, c3.y, acc[13]);
                acc[14] = fmaf(a, c3.z, acc[14]); acc[15] = fmaf(a, c3.w, acc[15]);
            }
        }
    }

    // Hs = prelu(acc @ W_s2^T)
    float hs[16], ht[16];
    {
        const float alpha = a_s2[0];
#pragma unroll
        for (int e = 0; e < 16; ++e) {
            float s = 0.f;
#pragma unroll
            for (int e2 = 0; e2 < 16; ++e2) s = fmaf(acc[e2], W_s2[e * 16 + e2], s);
            hs[e] = (s >= 0.f) ? s : alpha * s;
        }
    }
    const size_t rowbase = ((size_t)(n * T_DIM + t) * H_DIM + h) * 16;
    {
        const float* htp = Ht_f + rowbase;
#pragma unroll
        for (int qq = 0; qq < 4; ++qq) {
            const float4 v = *(const float4*)(htp + 4 * qq);
            ht[4*qq] = v.x; ht[4*qq+1] = v.y; ht[4*qq+2] = v.z; ht[4*qq+3] = v.w;
        }
    }

    // MLP: h = tanh(comb @ Wm1^T + bm1); z = h @ Wm2^T + bm2; 2-way softmax == sigmoid
    float z0 = bm2[0], z1 = bm2[1];
    for (int j = 0; j < 64; ++j) {
        float s = bm1[j];
        const float* w = Wm1 + j * 32;  // uniform -> s_load
#pragma unroll
        for (int i = 0; i < 16; ++i) s = fmaf(hs[i], w[i], s);
#pragma unroll
        for (int i = 0; i < 16; ++i) s = fmaf(ht[i], w[16 + i], s);
        const float e = __expf(2.0f * s);
        const float hj = 1.0f - 2.0f * __builtin_amdgcn_rcpf(1.0f + e);
        z0 = fmaf(hj, Wm2[j], z0);
        z1 = fmaf(hj, Wm2[64 + j], z1);
    }
    const float w0 = __builtin_amdgcn_rcpf(1.0f + __expf(z1 - z0));
    const float w1 = 1.0f - w0;

    float* op = out + rowbase;
#pragma unroll
    for (int qq = 0; qq < 4; ++qq) {
        *(float4*)(op + 4 * qq) = make_float4(
            fmaf(w0, hs[4*qq+0], w1 * ht[4*qq+0]),
            fmaf(w0, hs[4*qq+1], w1 * ht[4*qq+1]),
            fmaf(w0, hs[4*qq+2], w1 * ht[4*qq+2]),
            fmaf(w0, hs[4*qq+3], w1 * ht[4*qq+3]));
    }
}

extern "C" void kernel_launch(void* const* d_in, const int* in_sizes, int n_in,
                              void* d_out, int out_size, void* d_ws, size_t ws_size,
                              hipStream_t stream)
{
    const float* graph = (const float*)d_in[0];
    const float* adj_s = (const float*)d_in[1];
    const float* adj_t = (const float*)d_in[2];
    const float* W_s1  = (const float*)d_in[3];
    const float* a_s1  = (const float*)d_in[4];
    const float* W_s2  = (const float*)d_in[5];
    const float* a_s2  = (const float*)d_in[6];
    const float* W_t1  = (const float*)d_in[7];
    const float* a_t1  = (const float*)d_in[8];
    const float* W_t2  = (const float*)d_in[9];
    const float* a_t2  = (const float*)d_in[10];
    const float* Wm1   = (const float*)d_in[11];
    const float* bm1   = (const float*)d_in[12];
    const float* Wm2   = (const float*)d_in[13];
    const float* bm2   = (const float*)d_in[14];
    float* out = (float*)d_out;

    float* ws = (float*)d_ws;
    float* B_pack  = ws;                        // 512*256*24   = 3,145,728 f32 (12.6 MB)
    float* B_pack2 = B_pack + 512 * 256 * 24;   // 1024*128*16  = 2,097,152 f32 ( 8.4 MB)
    float* Ht_f    = B_pack2 + 1024 * 128 * 16; // 256*128*4*16 = 2,097,152 f32 ( 8.4 MB)

    k1_l1t   <<<dim3(N_DIM, H_DIM, 2), 64, 0, stream>>>(graph, adj_t, W_t1, a_t1, B_pack);
    k2_l1s_ht<<<dim3(T_DIM, H_DIM, 4), 64, 0, stream>>>(adj_s, B_pack, W_s1, a_s1, W_t2, a_t2,
                                                        B_pack2, Ht_f);
    k3_hs_mlp<<<dim3(N_DIM, H_DIM, 2), 64, 0, stream>>>(adj_t, B_pack2, W_s2, a_s2, Ht_f,
                                                        Wm1, bm1, Wm2, bm2, out);
}

// Round 6
// 531.158 us; speedup vs baseline: 1.0480x; 1.0480x over previous
//
#include <hip/hip_runtime.h>

// Fused spatio-temporal GCN, MI355X (gfx950), fp32 (no fp32 MFMA -> vector ALU).
// T=128, N=256, H=4, EMB=16, IN_DIMS=5, HID=64.
//
// R4 kernel, third submission (two GPUAcquisitionTimeouts; never executed).
// Occupancy fix: R1-R3 counters show latency-bound at <=20% occupancy
// (grid cap 2048 waves), FETCH < input (LLC-resident), conflicts 0.
// Structure: K-SPLIT x4 inside 256-thread blocks.
//   - all 4 waves own the same 64 output rows; wave w accumulates K-quarter
//     (R1-proven row-per-lane float4 loads straight to registers; B rows are
//     wave-uniform -> scalar loads; no staging, no barriers in the hot loop)
//   - one __syncthreads; partials summed via odd-padded LDS (no conflicts)
//   - epilogue spread across waves (K3's MLP: 4 lanes/row + quad shfl_xor)
// Grid: 2048 blocks x 4 waves = 32 waves/CU demand (vs 8 before).

#define T_DIM 128
#define N_DIM 256
#define H_DIM 4

// ---------------- K1: l1t -> B_pack[t][h][n][8..23]; h==0 also fills spa cols 0..4 ----
__global__ __launch_bounds__(256) void k1_l1t(
    const float* __restrict__ graph, const float* __restrict__ adj_t,
    const float* __restrict__ W_t1, const float* __restrict__ a_t1,
    float* __restrict__ B_pack)
{
    __shared__ float red[4 * 64 * 7];   // 7KB, odd stride -> conflict-free
    const int n = blockIdx.x, h = blockIdx.y, rb = blockIdx.z;
    const int tid = threadIdx.x, w = tid >> 6, lane = tid & 63;
    const int t = rb * 64 + lane;

    const float* arow = adj_t + ((size_t)((n * H_DIM + h) * T_DIM + t)) * T_DIM + w * 32;

    float acc[5] = {0.f, 0.f, 0.f, 0.f, 0.f};
#pragma unroll
    for (int k0 = 0; k0 < 32; k0 += 4) {
        const float4 a4 = *(const float4*)(arow + k0);
        const float av[4] = {a4.x, a4.y, a4.z, a4.w};
#pragma unroll
        for (int j = 0; j < 4; ++j) {
            const int k = w * 32 + k0 + j;
            const float* b = graph + (k * N_DIM + n) * 6 + 1;  // wave-uniform -> s_load
            const float a = av[j];
#pragma unroll
            for (int d = 0; d < 5; ++d) acc[d] = fmaf(a, b[d], acc[d]);
        }
    }
    float* rp = red + (w * 64 + lane) * 7;
#pragma unroll
    for (int d = 0; d < 5; ++d) rp[d] = acc[d];
    __syncthreads();

    if (lane < 16) {
        const int r = w * 16 + lane;
        const int tt = rb * 64 + r;
        float s[5];
#pragma unroll
        for (int d = 0; d < 5; ++d)
            s[d] = (red[(0 * 64 + r) * 7 + d] + red[(1 * 64 + r) * 7 + d]) +
                   (red[(2 * 64 + r) * 7 + d] + red[(3 * 64 + r) * 7 + d]);

        const float alpha = a_t1[0];
        float v[16];
#pragma unroll
        for (int e = 0; e < 16; ++e) {
            float p = 0.f;
#pragma unroll
            for (int d = 0; d < 5; ++d) p = fmaf(s[d], W_t1[e * 5 + d], p);
            v[e] = (p >= 0.f) ? p : alpha * p;
        }
        float* dst = B_pack + ((size_t)(tt * H_DIM + h) * N_DIM + n) * 24 + 8;
#pragma unroll
        for (int q = 0; q < 4; ++q)
            *(float4*)(dst + 4 * q) = make_float4(v[4*q], v[4*q+1], v[4*q+2], v[4*q+3]);

        if (h == 0) {
            const float* g = graph + (tt * N_DIM + n) * 6 + 1;
            const float s0 = g[0], s1 = g[1], s2 = g[2], s3 = g[3], s4 = g[4];
#pragma unroll
            for (int hh = 0; hh < H_DIM; ++hh) {
                float* sd = B_pack + ((size_t)(tt * H_DIM + hh) * N_DIM + n) * 24;
                sd[0] = s0; sd[1] = s1; sd[2] = s2; sd[3] = s3; sd[4] = s4;
            }
        }
    }
}

// ---------------- K2: C = adj_s[t,h] @ B_pack -> l1s (B_pack2) + Ht (Ht_f) ----------
__global__ __launch_bounds__(256) void k2_l1s_ht(
    const float* __restrict__ adj_s, const float* __restrict__ B_pack,
    const float* __restrict__ W_s1, const float* __restrict__ a_s1,
    const float* __restrict__ W_t2, const float* __restrict__ a_t2,
    float* __restrict__ B_pack2, float* __restrict__ Ht_f)
{
    __shared__ float red[4 * 64 * 23];  // 23.5KB, odd stride -> conflict-free
    const int t = blockIdx.x, h = blockIdx.y, q = blockIdx.z;
    const int tid = threadIdx.x, w = tid >> 6, lane = tid & 63;
    const int n = q * 64 + lane;

    const float* arow = adj_s + ((size_t)((t * H_DIM + h) * N_DIM + n)) * N_DIM + w * 64;
    const float* bp = B_pack + (size_t)(t * H_DIM + h) * (N_DIM * 24);

    float acc[21];
#pragma unroll
    for (int i = 0; i < 21; ++i) acc[i] = 0.f;

#pragma unroll 4
    for (int k0 = 0; k0 < 64; k0 += 4) {
        const float4 a4 = *(const float4*)(arow + k0);
        const float av[4] = {a4.x, a4.y, a4.z, a4.w};
#pragma unroll
        for (int j = 0; j < 4; ++j) {
            const float* b = bp + (w * 64 + k0 + j) * 24;  // wave-uniform -> s_load
            const float a = av[j];
            const float4 b0 = *(const float4*)(b);
            const float  b4 = b[4];
            const float4 c0 = *(const float4*)(b + 8);
            const float4 c1 = *(const float4*)(b + 12);
            const float4 c2 = *(const float4*)(b + 16);
            const float4 c3 = *(const float4*)(b + 20);
            acc[0] = fmaf(a, b0.x, acc[0]);  acc[1] = fmaf(a, b0.y, acc[1]);
            acc[2] = fmaf(a, b0.z, acc[2]);  acc[3] = fmaf(a, b0.w, acc[3]);
            acc[4] = fmaf(a, b4,   acc[4]);
            acc[5]  = fmaf(a, c0.x, acc[5]);  acc[6]  = fmaf(a, c0.y, acc[6]);
            acc[7]  = fmaf(a, c0.z, acc[7]);  acc[8]  = fmaf(a, c0.w, acc[8]);
            acc[9]  = fmaf(a, c1.x, acc[9]);  acc[10] = fmaf(a, c1.y, acc[10]);
            acc[11] = fmaf(a, c1.z, acc[11]); acc[12] = fmaf(a, c1.w, acc[12]);
            acc[13] = fmaf(a, c2.x, acc[13]); acc[14] = fmaf(a, c2.y, acc[14]);
            acc[15] = fmaf(a, c2.z, acc[15]); acc[16] = fmaf(a, c2.w, acc[16]);
            acc[17] = fmaf(a, c3.x, acc[17]); acc[18] = fmaf(a, c3.y, acc[18]);
            acc[19] = fmaf(a, c3.z, acc[19]); acc[20] = fmaf(a, c3.w, acc[20]);
        }
    }
    float* rp = red + (w * 64 + lane) * 23;
#pragma unroll
    for (int i = 0; i < 21; ++i) rp[i] = acc[i];
    __syncthreads();

    if (lane < 16) {
        const int r = w * 16 + lane;
        const int nn = q * 64 + r;
        float s[21];
#pragma unroll
        for (int i = 0; i < 21; ++i)
            s[i] = (red[(0 * 64 + r) * 23 + i] + red[(1 * 64 + r) * 23 + i]) +
                   (red[(2 * 64 + r) * 23 + i] + red[(3 * 64 + r) * 23 + i]);

        // l1s = prelu(C_spa @ W_s1^T) -> B_pack2[n][h][t][e]
        {
            const float alpha = a_s1[0];
            float v[16];
#pragma unroll
            for (int e = 0; e < 16; ++e) {
                float p = 0.f;
#pragma unroll
                for (int d = 0; d < 5; ++d) p = fmaf(s[d], W_s1[e * 5 + d], p);
                v[e] = (p >= 0.f) ? p : alpha * p;
            }
            float* dst = B_pack2 + ((size_t)(nn * H_DIM + h) * T_DIM + t) * 16;
#pragma unroll
            for (int qq = 0; qq < 4; ++qq)
                *(float4*)(dst + 4 * qq) = make_float4(v[4*qq], v[4*qq+1], v[4*qq+2], v[4*qq+3]);
        }
        // Ht = prelu(C_l1t @ W_t2^T) -> Ht_f[n][t][h][e]
        {
            const float alpha = a_t2[0];
            float v[16];
#pragma unroll
            for (int e = 0; e < 16; ++e) {
                float p = 0.f;
#pragma unroll
                for (int e2 = 0; e2 < 16; ++e2) p = fmaf(s[5 + e2], W_t2[e * 16 + e2], p);
                v[e] = (p >= 0.f) ? p : alpha * p;
            }
            float* dst = Ht_f + ((size_t)(nn * T_DIM + t) * H_DIM + h) * 16;
#pragma unroll
            for (int qq = 0; qq < 4; ++qq)
                *(float4*)(dst + 4 * qq) = make_float4(v[4*qq], v[4*qq+1], v[4*qq+2], v[4*qq+3]);
        }
    }
}

// ---------------- K3: Hs + fused MLP/softmax/blend -> out[n][t][h][:] ----------------
__global__ __launch_bounds__(256) void k3_hs_mlp(
    const float* __restrict__ adj_t, const float* __restrict__ B_pack2,
    const float* __restrict__ W_s2, const float* __restrict__ a_s2,
    const float* __restrict__ Ht_f,
    const float* __restrict__ Wm1, const float* __restrict__ bm1,
    const float* __restrict__ Wm2, const float* __restrict__ bm2,
    float* __restrict__ out)
{
    __shared__ float red[4 * 64 * 17];  // 17.4KB, odd stride -> conflict-free
    const int n = blockIdx.x, h = blockIdx.y, rb = blockIdx.z;
    const int tid = threadIdx.x, w = tid >> 6, lane = tid & 63;
    const int t = rb * 64 + lane;

    const float* arow = adj_t + ((size_t)((n * H_DIM + h) * T_DIM + t)) * T_DIM + w * 32;
    const float* bp = B_pack2 + (size_t)(n * H_DIM + h) * (T_DIM * 16);

    float acc[16];
#pragma unroll
    for (int i = 0; i < 16; ++i) acc[i] = 0.f;

#pragma unroll
    for (int k0 = 0; k0 < 32; k0 += 4) {
        const float4 a4 = *(const float4*)(arow + k0);
        const float av[4] = {a4.x, a4.y, a4.z, a4.w};
#pragma unroll
        for (int j = 0; j < 4; ++j) {
            const float* b = bp + (w * 32 + k0 + j) * 16;  // wave-uniform -> s_load
            const float a = av[j];
            const float4 c0 = *(const float4*)(b);
            const float4 c1 = *(const float4*)(b + 4);
            const float4 c2 = *(const float4*)(b + 8);
            const float4 c3 = *(const float4*)(b + 12);
            acc[0]  = fmaf(a, c0.x, acc[0]);  acc[1]  = fmaf(a, c0.y, acc[1]);
            acc[2]  = fmaf(a, c0.z, acc[2]);  acc[3]  = fmaf(a, c0.w, acc[3]);
            acc[4]  = fmaf(a, c1.x, acc[4]);  acc[5]  = fmaf(a, c1.y, acc[5]);
            acc[6]  = fmaf(a, c1.z, acc[6]);  acc[7]  = fmaf(a, c1.w, acc[7]);
            acc[8]  = fmaf(a, c2.x, acc[8]);  acc[9]  = fmaf(a, c2.y, acc[9]);
            acc[10] = fmaf(a, c2.z, acc[10]); acc[11] = fmaf(a, c2.w, acc[11]);
            acc[12] = fmaf(a, c3.x, acc[12]); acc[13] = fmaf(a, c3.y, acc[13]);
            acc[14] = fmaf(a, c3.z, acc[14]); acc[15] = fmaf(a, c3.w, acc[15]);
        }
    }
    float* rp = red + (w * 64 + lane) * 17;
#pragma unroll
    for (int i = 0; i < 16; ++i) rp[i] = acc[i];
    __syncthreads();

    // Epilogue: 4 lanes per row; lane quad p handles MLP j-range [16p,16p+16)
    const int r = w * 16 + (lane >> 2);
    const int p = lane & 3;
    const int tt = rb * 64 + r;

    float s[16];
#pragma unroll
    for (int e = 0; e < 16; ++e)
        s[e] = (red[(0 * 64 + r) * 17 + e] + red[(1 * 64 + r) * 17 + e]) +
               (red[(2 * 64 + r) * 17 + e] + red[(3 * 64 + r) * 17 + e]);

    // Hs = prelu(s @ W_s2^T)
    float hs[16], ht[16];
    {
        const float alpha = a_s2[0];
#pragma unroll
        for (int e = 0; e < 16; ++e) {
            float pr = 0.f;
#pragma unroll
            for (int e2 = 0; e2 < 16; ++e2) pr = fmaf(s[e2], W_s2[e * 16 + e2], pr);
            hs[e] = (pr >= 0.f) ? pr : alpha * pr;
        }
    }
    const size_t rowbase = ((size_t)(n * T_DIM + tt) * H_DIM + h) * 16;
    {
        const float* htp = Ht_f + rowbase;
#pragma unroll
        for (int qq = 0; qq < 4; ++qq) {
            const float4 v = *(const float4*)(htp + 4 * qq);
            ht[4*qq] = v.x; ht[4*qq+1] = v.y; ht[4*qq+2] = v.z; ht[4*qq+3] = v.w;
        }
    }

    // MLP partial over j in [16p, 16p+16)
    float z0 = 0.f, z1 = 0.f;
#pragma unroll
    for (int jj = 0; jj < 16; ++jj) {
        const int j = p * 16 + jj;
        float sv = bm1[j];
        const float* wv = Wm1 + j * 32;
#pragma unroll
        for (int i = 0; i < 16; ++i) sv = fmaf(hs[i], wv[i], sv);
#pragma unroll
        for (int i = 0; i < 16; ++i) sv = fmaf(ht[i], wv[16 + i], sv);
        const float e = __expf(2.0f * sv);
        const float hj = 1.0f - 2.0f * __builtin_amdgcn_rcpf(1.0f + e);
        z0 = fmaf(hj, Wm2[j], z0);
        z1 = fmaf(hj, Wm2[64 + j], z1);
    }
    // quad reduce
    z0 += __shfl_xor(z0, 1); z0 += __shfl_xor(z0, 2);
    z1 += __shfl_xor(z1, 1); z1 += __shfl_xor(z1, 2);
    z0 += bm2[0]; z1 += bm2[1];

    const float w0 = __builtin_amdgcn_rcpf(1.0f + __expf(z1 - z0));
    const float w1 = 1.0f - w0;

    float* op = out + rowbase + 4 * p;
    *(float4*)(op) = make_float4(
        fmaf(w0, hs[4*p+0], w1 * ht[4*p+0]),
        fmaf(w0, hs[4*p+1], w1 * ht[4*p+1]),
        fmaf(w0, hs[4*p+2], w1 * ht[4*p+2]),
        fmaf(w0, hs[4*p+3], w1 * ht[4*p+3]));
}

extern "C" void kernel_launch(void* const* d_in, const int* in_sizes, int n_in,
                              void* d_out, int out_size, void* d_ws, size_t ws_size,
                              hipStream_t stream)
{
    const float* graph = (const float*)d_in[0];
    const float* adj_s = (const float*)d_in[1];
    const float* adj_t = (const float*)d_in[2];
    const float* W_s1  = (const float*)d_in[3];
    const float* a_s1  = (const float*)d_in[4];
    const float* W_s2  = (const float*)d_in[5];
    const float* a_s2  = (const float*)d_in[6];
    const float* W_t1  = (const float*)d_in[7];
    const float* a_t1  = (const float*)d_in[8];
    const float* W_t2  = (const float*)d_in[9];
    const float* a_t2  = (const float*)d_in[10];
    const float* Wm1   = (const float*)d_in[11];
    const float* bm1   = (const float*)d_in[12];
    const float* Wm2   = (const float*)d_in[13];
    const float* bm2   = (const float*)d_in[14];
    float* out = (float*)d_out;

    float* ws = (float*)d_ws;
    float* B_pack  = ws;                        // 512*256*24   = 3,145,728 f32 (12.6 MB)
    float* B_pack2 = B_pack + 512 * 256 * 24;   // 1024*128*16  = 2,097,152 f32 ( 8.4 MB)
    float* Ht_f    = B_pack2 + 1024 * 128 * 16; // 256*128*4*16 = 2,097,152 f32 ( 8.4 MB)

    k1_l1t   <<<dim3(N_DIM, H_DIM, 2), 256, 0, stream>>>(graph, adj_t, W_t1, a_t1, B_pack);
    k2_l1s_ht<<<dim3(T_DIM, H_DIM, 4), 256, 0, stream>>>(adj_s, B_pack, W_s1, a_s1, W_t2, a_t2,
                                                         B_pack2, Ht_f);
    k3_hs_mlp<<<dim3(N_DIM, H_DIM, 2), 256, 0, stream>>>(adj_t, B_pack2, W_s2, a_s2, Ht_f,
                                                         Wm1, bm1, Wm2, bm2, out);
}